// Round 12
// baseline (302.143 us; speedup 1.0000x reference)
//
#include <hip/hip_runtime.h>
#include <hip/hip_fp16.h>

#define N_NODES 100000
#define N_EDGES 1600000
#define N_GRAPHS 128
#define SB 391               // 256-node buckets
#define CAP 4608             // padded bucket capacity (mean 4096 + 8 sigma)
#define NBLK 512             // blocks for the fused scatter pass
#define NE4 (N_EDGES / 4)    // 400000 int4
#define CH4 782              // int4 per block (512*782 >= 400000)
#define CMAX 3200            // max entries per block (782*4 = 3128)
#define LDX 136              // LDS stride (halves) for MFMA staging
#define EW 576               // per-wave staged edge slots (mean 256 + 20 sigma)

typedef unsigned long long u64;
typedef unsigned int u32;
typedef unsigned short u16;
typedef unsigned char u8;
typedef _Float16 f16;
typedef f16 half8 __attribute__((ext_vector_type(8)));
typedef f16 half4v __attribute__((ext_vector_type(4)));
typedef float floatx4 __attribute__((ext_vector_type(4)));

// ---------------- P1: fused count + reserve + LDS-grouped coalesced scatter --------
// v3: ssk8 side-pipeline removed — out-degrees go straight to a global counter
// array via atomicAdd (the whole src bucket-sort existed only to histogram them).
__global__ __launch_bounds__(256) void k_fuse(const int4* __restrict__ src4,
                                              const int4* __restrict__ dst4,
                                              int* __restrict__ cur_d,
                                              int* __restrict__ deg_out_i,
                                              u32* __restrict__ ed) {
  __shared__ int hd[SB], ld[SB], lofsD[SB], curD[SB];
  __shared__ int S[512];
  __shared__ u32 edbuf[CMAX];
  __shared__ u16 bidD[CMAX];
  const int t = threadIdx.x, b = blockIdx.x;
  for (int j = t; j < SB; j += 256) hd[j] = 0;
  __syncthreads();
  const int start = b * CH4, end = min(start + CH4, NE4);
  const int nit = end - start;                    // int4s this block (<= CH4)

  // load chunk into registers once
  int4 sv[4], dv[4];
  int nh = 0;
  #pragma unroll
  for (int k = 0; k < 4; ++k) {
    int i = start + t + 256 * k;
    if (i < nit + start) { sv[k] = src4[i]; dv[k] = dst4[i]; nh = k + 1; }
  }

  // count dst buckets (LDS) + out-degrees (global atomics, ~100K L2 counters)
  #pragma unroll
  for (int k = 0; k < 4; ++k) {
    if (k < nh) {
      int4 d = dv[k]; int4 s = sv[k];
      atomicAdd(&hd[d.x >> 8], 1); atomicAdd(&hd[d.y >> 8], 1);
      atomicAdd(&hd[d.z >> 8], 1); atomicAdd(&hd[d.w >> 8], 1);
      atomicAdd(&deg_out_i[s.x], 1); atomicAdd(&deg_out_i[s.y], 1);
      atomicAdd(&deg_out_i[s.z], 1); atomicAdd(&deg_out_i[s.w], 1);
    }
  }
  __syncthreads();

  // global reserve (one atomic per bucket per block); cursors bucket-relative
  for (int j = t; j < SB; j += 256)
    ld[j] = j * CAP + atomicAdd(&cur_d[j], hd[j]);

  // exclusive scan of hd -> lofsD (512-wide Hillis-Steele, 2 elems/thread)
  S[t] = (t < SB) ? hd[t] : 0;
  S[t + 256] = (t + 256 < SB) ? hd[t + 256] : 0;
  __syncthreads();
  for (int off = 1; off < 512; off <<= 1) {
    int a0 = (t >= off) ? S[t - off] : 0;
    int a1 = (t + 256 >= off) ? S[t + 256 - off] : 0;
    __syncthreads();
    S[t] += a0; S[t + 256] += a1;
    __syncthreads();
  }
  if (t < SB) { lofsD[t] = S[t] - hd[t]; curD[t] = S[t] - hd[t]; }
  if (t + 256 < SB) { lofsD[t + 256] = S[t + 256] - hd[t + 256]; curD[t + 256] = S[t + 256] - hd[t + 256]; }
  __syncthreads();

  // local scatter from regs into LDS groups
  #pragma unroll
  for (int k = 0; k < 4; ++k) {
    if (k < nh) {
      int4 d4 = dv[k]; int4 s4 = sv[k];
      {
        int d = d4.x, s = s4.x; int j = d >> 8;
        int p = atomicAdd(&curD[j], 1);
        edbuf[p] = ((u32)(d & 255) << 24) | (u32)s; bidD[p] = (u16)j;
      }
      {
        int d = d4.y, s = s4.y; int j = d >> 8;
        int p = atomicAdd(&curD[j], 1);
        edbuf[p] = ((u32)(d & 255) << 24) | (u32)s; bidD[p] = (u16)j;
      }
      {
        int d = d4.z, s = s4.z; int j = d >> 8;
        int p = atomicAdd(&curD[j], 1);
        edbuf[p] = ((u32)(d & 255) << 24) | (u32)s; bidD[p] = (u16)j;
      }
      {
        int d = d4.w, s = s4.w; int j = d >> 8;
        int p = atomicAdd(&curD[j], 1);
        edbuf[p] = ((u32)(d & 255) << 24) | (u32)s; bidD[p] = (u16)j;
      }
    }
  }
  __syncthreads();

  // copy grouped runs out (consecutive i within a bucket -> consecutive gaddr)
  const int cnt = nit * 4;
  for (int i = t; i < cnt; i += 256) {
    int j = bidD[i];
    ed[ld[j] + i - lofsD[j]] = edbuf[i];
  }
}

// ------ P2: per-bucket CSR finalize + degrees/norms (padded bucket space) ----------
__global__ __launch_bounds__(256) void k_bucket_csr(const u32* __restrict__ ed,
                                                    const int* __restrict__ cur_d,
                                                    const int* __restrict__ deg_out_i,
                                                    int* __restrict__ row_ptr,
                                                    int* __restrict__ deg,
                                                    float* __restrict__ norm_in,
                                                    float* __restrict__ norm_out,
                                                    int* __restrict__ edge_src) {
  __shared__ int hist[256], scanbuf[256], cursor[256];
  const int b = blockIdx.x, t = threadIdx.x;
  const int base = b << 8;
  const int lo = b * CAP;
  const int hiD = lo + cur_d[b];   // cursors are relative counts
  hist[t] = 0;
  __syncthreads();
  for (int i = lo + t; i < hiD; i += 256) atomicAdd(&hist[ed[i] >> 24], 1);
  __syncthreads();
  int node = base + t;
  if (node < N_NODES)
    norm_out[node] = rsqrtf(fmaxf((float)deg_out_i[node], 1.0f));
  int v = hist[t];
  scanbuf[t] = v;
  __syncthreads();
  for (int off = 1; off < 256; off <<= 1) {
    int a = (t >= off) ? scanbuf[t - off] : 0;
    __syncthreads(); scanbuf[t] += a; __syncthreads();
  }
  int excl = scanbuf[t] - v;
  if (node < N_NODES) {
    row_ptr[node] = lo + excl;
    deg[node] = v;
    norm_in[node] = rsqrtf(fmaxf((float)v, 1.0f));
  }
  cursor[t] = excl;
  __syncthreads();
  for (int i = lo + t; i < hiD; i += 256) {
    u32 e = ed[i];
    int p = atomicAdd(&cursor[e >> 24], 1);
    edge_src[lo + p] = (int)(e & 0x00FFFFFFu);
  }
}

// ---------------- P3: gemm1 (MFMA fp16): h1 = (x * norm_out) @ W1 -> fp16 ----------
__global__ __launch_bounds__(256) void k_gemm1(const float* __restrict__ x,
                                               const float* __restrict__ W1,
                                               const float* __restrict__ norm_out,
                                               __half* __restrict__ h1h) {
  __shared__ __align__(16) f16 Xs[64 * LDX];
  __shared__ __align__(16) f16 Ws[64 * LDX];
  const int t = threadIdx.x;
  const int row0 = blockIdx.x * 64;

  const float4* W4 = (const float4*)W1;     // 2048 float4 = [k][n4]
  for (int i = t; i < 2048; i += 256) {
    int k = i >> 4, n4 = (i & 15) * 4;
    float4 v = W4[i];
    Ws[(n4 + 0) * LDX + k] = (f16)v.x;
    Ws[(n4 + 1) * LDX + k] = (f16)v.y;
    Ws[(n4 + 2) * LDX + k] = (f16)v.z;
    Ws[(n4 + 3) * LDX + k] = (f16)v.w;
  }
  const float4* x4 = (const float4*)x;
  #pragma unroll
  for (int i = 0; i < 8; ++i) {
    int idx = t + 256 * i;                  // 0..2047
    int r = idx >> 5, c4 = idx & 31;
    int row = row0 + r;
    float4 v = make_float4(0.f, 0.f, 0.f, 0.f);
    if (row < N_NODES) {
      float s = norm_out[row];
      v = x4[(size_t)row * 32 + c4];
      v.x *= s; v.y *= s; v.z *= s; v.w *= s;
    }
    half4v h = { (f16)v.x, (f16)v.y, (f16)v.z, (f16)v.w };
    *(half4v*)&Xs[r * LDX + c4 * 4] = h;
  }
  __syncthreads();

  const int w = t >> 6, l = t & 63;
  const int m = l & 15, quad = l >> 4;
  floatx4 c0 = {0.f,0.f,0.f,0.f}, c1 = {0.f,0.f,0.f,0.f};
  floatx4 c2 = {0.f,0.f,0.f,0.f}, c3 = {0.f,0.f,0.f,0.f};
  const f16* xrow = &Xs[(w * 16 + m) * LDX + quad * 8];
  const f16* wrow = &Ws[m * LDX + quad * 8];
  #pragma unroll
  for (int kb = 0; kb < 4; ++kb) {
    half8 a  = *(const half8*)(xrow + kb * 32);
    half8 b0 = *(const half8*)(wrow + kb * 32);
    half8 b1 = *(const half8*)(wrow + 16 * LDX + kb * 32);
    half8 b2 = *(const half8*)(wrow + 32 * LDX + kb * 32);
    half8 b3 = *(const half8*)(wrow + 48 * LDX + kb * 32);
    c0 = __builtin_amdgcn_mfma_f32_16x16x32_f16(a, b0, c0, 0, 0, 0);
    c1 = __builtin_amdgcn_mfma_f32_16x16x32_f16(a, b1, c1, 0, 0, 0);
    c2 = __builtin_amdgcn_mfma_f32_16x16x32_f16(a, b2, c2, 0, 0, 0);
    c3 = __builtin_amdgcn_mfma_f32_16x16x32_f16(a, b3, c3, 0, 0, 0);
  }
  #pragma unroll
  for (int r = 0; r < 4; ++r) {
    int row = row0 + w * 16 + quad * 4 + r;
    if (row < N_NODES + 1) {                // includes zeros dummy row N_NODES
      __half* dst = h1h + (size_t)row * 64 + m;
      dst[0]  = __float2half(c0[r]);
      dst[16] = __float2half(c1[r]);
      dst[32] = __float2half(c2[r]);
      dst[48] = __float2half(c3[r]);
    }
  }
}

// ---------------- P4: fused gather(h1) -> relu -> @W2 -> h2, all-register MFMA ----
// (R10 proven form: LDS edge-index staging + depth-2 load slots.)
__global__ __launch_bounds__(256) void k_gather_l1(const int* __restrict__ row_ptr,
                                                   const int* __restrict__ deg,
                                                   const int* __restrict__ edge_src,
                                                   const __half* __restrict__ h1h,
                                                   const float* __restrict__ norm_in,
                                                   const float* __restrict__ norm_out,
                                                   const float* __restrict__ b1,
                                                   const float* __restrict__ W2,
                                                   __half* __restrict__ h2h) {
  __shared__ __align__(16) f16 Ws2[16 * 72];      // W2^T [n][k], stride 72
  __shared__ __align__(16) f16 Rs[4][16 * 72];    // per-wave relu vecs [node][feat]
  __shared__ int Eidx[4][EW];                     // per-wave staged edge list
  const int t = threadIdx.x;
  for (int i = t; i < 1024; i += 256) {           // W2 [64][16] row-major
    int k = i >> 4, n = i & 15;
    Ws2[n * 72 + k] = (f16)W2[i];
  }
  if (blockIdx.x == 0 && t < 16) h2h[(size_t)N_NODES * 16 + t] = __float2half(0.f);
  __syncthreads();

  const int w = t >> 6, l = t & 63;
  const int base = blockIdx.x * 64 + w * 16;
  if (base >= N_NODES) return;

  const int m = l & 15, q4 = l >> 4;              // fragment coords
  const int node_l = min(base + m, N_NODES - 1);
  const int my_lo = row_ptr[node_l];
  const u32 my_deg = (u32)deg[node_l];
  const int lo_blk = __shfl(my_lo, 0, 64);
  const int hi_blk = __shfl(my_lo + (int)my_deg, 15, 64);
  const int nE = min(hi_blk - lo_blk, EW);        // EW = mean+20sigma, never binds

  // stage the wave's edge list (coalesced, sequential)
  for (int i = l; i < nE; i += 64) Eidx[w][i] = edge_src[lo_blk + i];
  asm volatile("s_waitcnt lgkmcnt(0)" ::: "memory");
  __builtin_amdgcn_sched_barrier(0);

  // gather permutations: lane's A-row m -> chunk-local edge sigma(m)
  const int s1e = 8 * (m >> 2) + (m & 3);
  const int s2e = s1e + 4;

  union U4 { u32 u[4]; half8 h; uint4 v; };

  // loop-invariant identity B-frags for stage1: B_ih[k][n] = (k == n + 16*ih)
  U4 ib0, ib1;
  #pragma unroll
  for (int wj = 0; wj < 4; ++wj) {
    int k0 = q4 * 8 + 2 * wj, k1 = k0 + 1;
    ib0.u[wj] = (k0 == m      ? 0x3C00u : 0u) | (k1 == m      ? 0x3C000000u : 0u);
    ib1.u[wj] = (k0 == m + 16 ? 0x3C00u : 0u) | (k1 == m + 16 ? 0x3C000000u : 0u);
  }

  const uint4* __restrict__ h1u4 = (const uint4*)h1h;
  floatx4 acc0 = {0.f,0.f,0.f,0.f}, acc1 = {0.f,0.f,0.f,0.f};
  floatx4 acc2 = {0.f,0.f,0.f,0.f}, acc3 = {0.f,0.f,0.f,0.f};
  const floatx4 zf = {0.f,0.f,0.f,0.f};

  uint4 pa0, pa1, pb0, pb1;   // slot A
  uint4 qa0, qa1, qb0, qb1;   // slot B
  #define LOADC(CB, R0, R1, R2, R3) do {                                      \
    int o1 = (CB) + s1e, o2 = (CB) + s2e;                                     \
    int sv1 = (o1 < nE) ? Eidx[w][o1] : (int)N_NODES;                         \
    int sv2 = (o2 < nE) ? Eidx[w][o2] : (int)N_NODES;                         \
    size_t r1 = (size_t)(u32)sv1 * 8u, r2 = (size_t)(u32)sv2 * 8u;            \
    R0 = h1u4[r1 + (u32)q4];       R1 = h1u4[r1 + 4u + (u32)q4];              \
    R2 = h1u4[r2 + (u32)q4];       R3 = h1u4[r2 + 4u + (u32)q4];              \
  } while (0)

  // 12 MFMAs for one 32-edge chunk held in (CA0,CA1,CB0,CB1), flags from E0
  #define CHUNK_MFMA(E0, CA0, CA1, CB0, CB1) do {                             \
    u32 e0 = (E0) + (u32)(q4 * 8);                                            \
    U4 s;                                                                     \
    s.u[0] = ((e0+0u)<my_deg?0x3C00u:0u) | ((e0+1u)<my_deg?0x3C000000u:0u);   \
    s.u[1] = ((e0+2u)<my_deg?0x3C00u:0u) | ((e0+3u)<my_deg?0x3C000000u:0u);   \
    s.u[2] = ((e0+4u)<my_deg?0x3C00u:0u) | ((e0+5u)<my_deg?0x3C000000u:0u);   \
    s.u[3] = ((e0+6u)<my_deg?0x3C00u:0u) | ((e0+7u)<my_deg?0x3C000000u:0u);   \
    {                                                                         \
      floatx4 o10 = __builtin_amdgcn_mfma_f32_16x16x32_f16(CA0.h, ib0.h, zf, 0, 0, 0); \
      floatx4 o11 = __builtin_amdgcn_mfma_f32_16x16x32_f16(CA0.h, ib1.h, zf, 0, 0, 0); \
      floatx4 o20 = __builtin_amdgcn_mfma_f32_16x16x32_f16(CB0.h, ib0.h, zf, 0, 0, 0); \
      floatx4 o21 = __builtin_amdgcn_mfma_f32_16x16x32_f16(CB0.h, ib1.h, zf, 0, 0, 0); \
      half8 bf0 = { (f16)o10[0], (f16)o10[1], (f16)o10[2], (f16)o10[3],       \
                    (f16)o20[0], (f16)o20[1], (f16)o20[2], (f16)o20[3] };     \
      half8 bf1 = { (f16)o11[0], (f16)o11[1], (f16)o11[2], (f16)o11[3],       \
                    (f16)o21[0], (f16)o21[1], (f16)o21[2], (f16)o21[3] };     \
      acc0 = __builtin_amdgcn_mfma_f32_16x16x32_f16(s.h, bf0, acc0, 0, 0, 0); \
      acc1 = __builtin_amdgcn_mfma_f32_16x16x32_f16(s.h, bf1, acc1, 0, 0, 0); \
    }                                                                         \
    {                                                                         \
      floatx4 o10 = __builtin_amdgcn_mfma_f32_16x16x32_f16(CA1.h, ib0.h, zf, 0, 0, 0); \
      floatx4 o11 = __builtin_amdgcn_mfma_f32_16x16x32_f16(CA1.h, ib1.h, zf, 0, 0, 0); \
      floatx4 o20 = __builtin_amdgcn_mfma_f32_16x16x32_f16(CB1.h, ib0.h, zf, 0, 0, 0); \
      floatx4 o21 = __builtin_amdgcn_mfma_f32_16x16x32_f16(CB1.h, ib1.h, zf, 0, 0, 0); \
      half8 bf0 = { (f16)o10[0], (f16)o10[1], (f16)o10[2], (f16)o10[3],       \
                    (f16)o20[0], (f16)o20[1], (f16)o20[2], (f16)o20[3] };     \
      half8 bf1 = { (f16)o11[0], (f16)o11[1], (f16)o11[2], (f16)o11[3],       \
                    (f16)o21[0], (f16)o21[1], (f16)o21[2], (f16)o21[3] };     \
      acc2 = __builtin_amdgcn_mfma_f32_16x16x32_f16(s.h, bf0, acc2, 0, 0, 0); \
      acc3 = __builtin_amdgcn_mfma_f32_16x16x32_f16(s.h, bf1, acc3, 0, 0, 0); \
    }                                                                         \
  } while (0)

  // prologue: fill both slots (clamped loads past nE hit the zeros row)
  LOADC(0,  pa0, pa1, pb0, pb1);
  LOADC(32, qa0, qa1, qb0, qb1);

  const u32 dlo = (u32)(lo_blk - my_lo);          // wraps; flags mask correctly
  #pragma unroll 1
  for (int cb = 0; cb < nE; cb += 64) {
    U4 ca0, ca1, cb0v, cb1v;
    ca0.v = pa0; ca1.v = pa1; cb0v.v = pb0; cb1v.v = pb1;
    LOADC(cb + 64, pa0, pa1, pb0, pb1);
    CHUNK_MFMA(dlo + (u32)cb, ca0, ca1, cb0v, cb1v);

    U4 da0, da1, db0, db1;
    da0.v = qa0; da1.v = qa1; db0.v = qb0; db1.v = qb1;
    LOADC(cb + 96, qa0, qa1, qb0, qb1);
    CHUNK_MFMA(dlo + (u32)(cb + 32), da0, da1, db0, db1);
  }
  #undef LOADC
  #undef CHUNK_MFMA

  // epilogue: D rows = nodes (q4*4+r), cols = feats 16g+m. relu(*ni + b1) -> Rs
  const float bg0 = b1[m], bg1 = b1[16 + m], bg2 = b1[32 + m], bg3 = b1[48 + m];
  f16* Rw = &Rs[w][0];
  #pragma unroll
  for (int r = 0; r < 4; ++r) {
    int row = base + q4 * 4 + r;
    float ni = (row < N_NODES) ? norm_in[row] : 0.f;
    f16* dst = &Rw[(q4 * 4 + r) * 72 + m];
    dst[0]  = (f16)fmaxf(acc0[r] * ni + bg0, 0.f);
    dst[16] = (f16)fmaxf(acc1[r] * ni + bg1, 0.f);
    dst[32] = (f16)fmaxf(acc2[r] * ni + bg2, 0.f);
    dst[48] = (f16)fmaxf(acc3[r] * ni + bg3, 0.f);
  }
  // drain the per-wave ds_writes before the cross-lane ds_reads of the tail
  asm volatile("s_waitcnt lgkmcnt(0)" ::: "memory");
  __builtin_amdgcn_sched_barrier(0);

  // W2 MFMA tail (same fragment indexing as k_gemm1), per-wave on its own Rs
  const f16* ra = &Rw[m * 72 + q4 * 8];
  const f16* rb = &Ws2[m * 72 + q4 * 8];
  half8 a0 = *(const half8*)ra;
  half8 a1 = *(const half8*)(ra + 32);
  half8 wb0 = *(const half8*)rb;
  half8 wb1 = *(const half8*)(rb + 32);
  floatx4 cc = {0.f,0.f,0.f,0.f};
  cc = __builtin_amdgcn_mfma_f32_16x16x32_f16(a0, wb0, cc, 0, 0, 0);
  cc = __builtin_amdgcn_mfma_f32_16x16x32_f16(a1, wb1, cc, 0, 0, 0);
  #pragma unroll
  for (int r = 0; r < 4; ++r) {
    int row = base + q4 * 4 + r;
    if (row < N_NODES)
      h2h[(size_t)row * 16 + m] = __float2half(cc[r] * norm_out[row]);
  }
}

// ---------------- P5: gather layer2: agg2 = norm_in * sum_edges h2[src] (16 feats) ------
__global__ __launch_bounds__(256) void k_gather_l2(const int* __restrict__ row_ptr,
                                                   const int* __restrict__ deg,
                                                   const int* __restrict__ edge_src,
                                                   const __half* __restrict__ h2h,
                                                   const float* __restrict__ norm_in,
                                                   float* __restrict__ agg2) {
  const int t = threadIdx.x;
  const int w = t >> 6;
  const int l = t & 63;
  const int n = blockIdx.x * 4 + w;
  const int f2 = l & 7;
  const int p = l >> 3;            // 8 edge slices

  const u32* __restrict__ h2u = (const u32*)h2h;
  const int lo = row_ptr[n], hi = lo + deg[n];

  float ax = 0.f, ay = 0.f, bx = 0.f, by = 0.f;
  for (int base = lo; base < hi; base += 16) {
    int i1 = base + p, i2 = base + p + 8;
    int s0 = (i1 < hi) ? edge_src[i1] : (int)N_NODES;
    int s1 = (i2 < hi) ? edge_src[i2] : (int)N_NODES;
    u32 v0 = h2u[(u32)s0 * 8u + (u32)f2];
    u32 v1 = h2u[(u32)s1 * 8u + (u32)f2];
    float2 g0 = __half22float2(*(__half2*)&v0);
    float2 g1 = __half22float2(*(__half2*)&v1);
    ax += g0.x; ay += g0.y;
    bx += g1.x; by += g1.y;
  }
  float sx = ax + bx, sy = ay + by;
  sx += __shfl_xor(sx, 8, 64);  sy += __shfl_xor(sy, 8, 64);
  sx += __shfl_xor(sx, 16, 64); sy += __shfl_xor(sy, 16, 64);
  sx += __shfl_xor(sx, 32, 64); sy += __shfl_xor(sy, 32, 64);
  if (l < 8) {
    float ni = norm_in[n];
    ((float2*)agg2)[(size_t)n * 8 + f2] = make_float2(sx * ni, sy * ni);
  }
}

// ---------------- P6: per-graph mean pool (gid sorted, no atomics) ----------------
__global__ __launch_bounds__(256) void k_pool(const float* __restrict__ agg2,
                                              const float* __restrict__ b2,
                                              const int* __restrict__ gid,
                                              float* __restrict__ out) {
  const int g = blockIdx.x;
  __shared__ int s_lo, s_hi;
  if (threadIdx.x == 0) {
    int a = 0, b = N_NODES;
    while (a < b) { int m = (a + b) >> 1; if (gid[m] < g) a = m + 1; else b = m; }
    s_lo = a;
    b = N_NODES;
    while (a < b) { int m = (a + b) >> 1; if (gid[m] < g + 1) a = m + 1; else b = m; }
    s_hi = a;
  }
  __syncthreads();
  const int lo = s_lo, hi = s_hi, cnt = hi - lo;
  const int j = threadIdx.x & 15;
  const int r = threadIdx.x >> 4;
  float acc = 0.f;
  for (int n = lo + r; n < hi; n += 16)
    acc += agg2[(size_t)n * 16 + j];

  __shared__ float red[256];
  red[threadIdx.x] = acc;
  __syncthreads();
  #pragma unroll
  for (int s = 8; s > 0; s >>= 1) {
    if (r < s) red[threadIdx.x] += red[threadIdx.x + s * 16];
    __syncthreads();
  }
  if (r == 0)
    out[g * 16 + j] = (cnt > 0) ? (red[j] / (float)cnt + b2[j]) : 0.0f;
}

extern "C" void kernel_launch(void* const* d_in, const int* in_sizes, int n_in,
                              void* d_out, int out_size, void* d_ws, size_t ws_size,
                              hipStream_t stream) {
  const float* x   = (const float*)d_in[0];
  const float* W1  = (const float*)d_in[1];
  const float* b1  = (const float*)d_in[2];
  const float* W2  = (const float*)d_in[3];
  const float* b2  = (const float*)d_in[4];
  const int*   src = (const int*)d_in[5];
  const int*   dst = (const int*)d_in[6];
  const int*   gid = (const int*)d_in[7];
  float* out = (float*)d_out;

  int* wsi = (int*)d_ws;
  float* wsf = (float*)d_ws;

  // word-offset layout (identical footprint to the proven R10 layout, ~24.8 MB):
  float* norm_out  = wsf + 0;                // [N]
  float* norm_in   = wsf + 100000;           // [N]
  int*   row_ptr   = wsi + 200000;           // [N]
  int*   deg       = wsi + 300000;           // [N]
  int*   cur_d     = wsi + 400000;           // [SB+pad=800] relative counts
  int*   edge_src  = wsi + 400800;           // [SB*CAP = 1801728]
  const size_t S   = 2202528;                // scratch base (words)
  // fuse/csr-phase scratch (dead after csr):
  int*   deg_out_i = (int*)(wsi + S);        // [N] out-degree counters (memset 0)
  u32*   ed        = (u32*)(wsi + S + 450432);// [SB*CAP = 1801728]
  // reuse after CSR build: h1h over {deg_out_i, ed}; h2h beyond; agg2 over h1h
  __half* h1h      = (__half*)(wsi + S);               // [(N+1)*64 halves = 3200032 words]
  __half* h2h      = (__half*)(wsi + S + 3200032);     // [(N+1)*16 halves = 800008 words]
  float*  agg2     = (float*)(wsi + S);                // [16N words] (h1h dead by then)

  const int4* src4 = (const int4*)src;
  const int4* dst4 = (const int4*)dst;

  hipMemsetAsync(cur_d, 0, 400 * sizeof(int), stream);
  hipMemsetAsync(deg_out_i, 0, N_NODES * sizeof(int), stream);
  k_fuse      <<<NBLK, 256, 0, stream>>>(src4, dst4, cur_d, deg_out_i, ed);
  k_bucket_csr<<<SB, 256, 0, stream>>>(ed, cur_d, deg_out_i, row_ptr, deg,
                                       norm_in, norm_out, edge_src);
  k_gemm1     <<<(N_NODES + 64) / 64, 256, 0, stream>>>(x, W1, norm_out, h1h);
  k_gather_l1 <<<(N_NODES + 63) / 64, 256, 0, stream>>>(row_ptr, deg, edge_src, h1h,
                                                        norm_in, norm_out, b1, W2, h2h);
  k_gather_l2 <<<N_NODES / 4, 256, 0, stream>>>(row_ptr, deg, edge_src, h2h,
                                                norm_in, agg2);
  k_pool      <<<N_GRAPHS, 256, 0, stream>>>(agg2, b2, gid, out);
}

// Round 13
// 251.620 us; speedup vs baseline: 1.2008x; 1.2008x over previous
//
#include <hip/hip_runtime.h>
#include <hip/hip_fp16.h>

#define N_NODES 100000
#define N_EDGES 1600000
#define N_GRAPHS 128
#define SB 391               // 256-node buckets
#define CAP 4608             // padded bucket capacity (mean 4096 + 8 sigma)
#define NBLK 512             // blocks for the fused scatter pass
#define NE4 (N_EDGES / 4)    // 400000 int4
#define CH4 782              // int4 per block (512*782 >= 400000)
#define CMAX 3200            // max entries per block per side (782*4 = 3128)
#define LDX 136              // LDS stride (halves) for MFMA staging
#define EW 576               // per-wave staged edge slots (mean 256 + 20 sigma)

typedef unsigned long long u64;
typedef unsigned int u32;
typedef unsigned short u16;
typedef unsigned char u8;
typedef _Float16 f16;
typedef f16 half8 __attribute__((ext_vector_type(8)));
typedef f16 half4v __attribute__((ext_vector_type(4)));
typedef float floatx4 __attribute__((ext_vector_type(4)));

// ---------------- P1: fused count + reserve + LDS-grouped coalesced scatter --------
__global__ __launch_bounds__(256) void k_fuse(const int4* __restrict__ src4,
                                              const int4* __restrict__ dst4,
                                              int* __restrict__ cur_d,
                                              int* __restrict__ cur_s,
                                              u32* __restrict__ ed,
                                              u8* __restrict__ ssk8) {
  __shared__ int hd[SB], hs[SB], ld[SB], ls[SB];
  __shared__ int lofsD[SB], lofsS[SB], curD[SB], curS[SB];
  __shared__ int S[512];
  __shared__ u32 edbuf[CMAX];
  __shared__ u16 bidD[CMAX], bidS[CMAX];
  __shared__ u8  ssbuf[CMAX];
  const int t = threadIdx.x, b = blockIdx.x;
  for (int j = t; j < SB; j += 256) { hd[j] = 0; hs[j] = 0; }
  __syncthreads();
  const int start = b * CH4, end = min(start + CH4, NE4);
  const int nit = end - start;                    // int4s this block (<= CH4)

  // load chunk into registers once
  int4 sv[4], dv[4];
  int nh = 0;
  #pragma unroll
  for (int k = 0; k < 4; ++k) {
    int i = start + t + 256 * k;
    if (i < nit + start) { sv[k] = src4[i]; dv[k] = dst4[i]; nh = k + 1; }
  }

  // pass A: count from regs
  #pragma unroll
  for (int k = 0; k < 4; ++k) {
    if (k < nh) {
      int4 d = dv[k]; int4 s = sv[k];
      atomicAdd(&hd[d.x >> 8], 1); atomicAdd(&hd[d.y >> 8], 1);
      atomicAdd(&hd[d.z >> 8], 1); atomicAdd(&hd[d.w >> 8], 1);
      atomicAdd(&hs[s.x >> 8], 1); atomicAdd(&hs[s.y >> 8], 1);
      atomicAdd(&hs[s.z >> 8], 1); atomicAdd(&hs[s.w >> 8], 1);
    }
  }
  __syncthreads();

  // global reserve (one atomic per bucket per block); cursors are bucket-relative
  for (int j = t; j < SB; j += 256) {
    ld[j] = j * CAP + atomicAdd(&cur_d[j], hd[j]);
    ls[j] = j * CAP + atomicAdd(&cur_s[j], hs[j]);
  }

  // exclusive scan of hd -> lofsD (512-wide Hillis-Steele, 2 elems/thread)
  S[t] = (t < SB) ? hd[t] : 0;
  S[t + 256] = (t + 256 < SB) ? hd[t + 256] : 0;
  __syncthreads();
  for (int off = 1; off < 512; off <<= 1) {
    int a0 = (t >= off) ? S[t - off] : 0;
    int a1 = (t + 256 >= off) ? S[t + 256 - off] : 0;
    __syncthreads();
    S[t] += a0; S[t + 256] += a1;
    __syncthreads();
  }
  if (t < SB) { lofsD[t] = S[t] - hd[t]; curD[t] = S[t] - hd[t]; }
  if (t + 256 < SB) { lofsD[t + 256] = S[t + 256] - hd[t + 256]; curD[t + 256] = S[t + 256] - hd[t + 256]; }
  __syncthreads();

  // exclusive scan of hs -> lofsS
  S[t] = (t < SB) ? hs[t] : 0;
  S[t + 256] = (t + 256 < SB) ? hs[t + 256] : 0;
  __syncthreads();
  for (int off = 1; off < 512; off <<= 1) {
    int a0 = (t >= off) ? S[t - off] : 0;
    int a1 = (t + 256 >= off) ? S[t + 256 - off] : 0;
    __syncthreads();
    S[t] += a0; S[t + 256] += a1;
    __syncthreads();
  }
  if (t < SB) { lofsS[t] = S[t] - hs[t]; curS[t] = S[t] - hs[t]; }
  if (t + 256 < SB) { lofsS[t + 256] = S[t + 256] - hs[t + 256]; curS[t + 256] = S[t + 256] - hs[t + 256]; }
  __syncthreads();

  // local scatter from regs into LDS groups
  #pragma unroll
  for (int k = 0; k < 4; ++k) {
    if (k < nh) {
      int4 d4 = dv[k]; int4 s4 = sv[k];
      {
        int d = d4.x, s = s4.x; int j = d >> 8;
        int p = atomicAdd(&curD[j], 1);
        edbuf[p] = ((u32)(d & 255) << 24) | (u32)s; bidD[p] = (u16)j;
        int js = s >> 8; int ps = atomicAdd(&curS[js], 1);
        ssbuf[ps] = (u8)(s & 255); bidS[ps] = (u16)js;
      }
      {
        int d = d4.y, s = s4.y; int j = d >> 8;
        int p = atomicAdd(&curD[j], 1);
        edbuf[p] = ((u32)(d & 255) << 24) | (u32)s; bidD[p] = (u16)j;
        int js = s >> 8; int ps = atomicAdd(&curS[js], 1);
        ssbuf[ps] = (u8)(s & 255); bidS[ps] = (u16)js;
      }
      {
        int d = d4.z, s = s4.z; int j = d >> 8;
        int p = atomicAdd(&curD[j], 1);
        edbuf[p] = ((u32)(d & 255) << 24) | (u32)s; bidD[p] = (u16)j;
        int js = s >> 8; int ps = atomicAdd(&curS[js], 1);
        ssbuf[ps] = (u8)(s & 255); bidS[ps] = (u16)js;
      }
      {
        int d = d4.w, s = s4.w; int j = d >> 8;
        int p = atomicAdd(&curD[j], 1);
        edbuf[p] = ((u32)(d & 255) << 24) | (u32)s; bidD[p] = (u16)j;
        int js = s >> 8; int ps = atomicAdd(&curS[js], 1);
        ssbuf[ps] = (u8)(s & 255); bidS[ps] = (u16)js;
      }
    }
  }
  __syncthreads();

  // copy grouped runs out (consecutive i within a bucket -> consecutive gaddr)
  const int cnt = nit * 4;
  for (int i = t; i < cnt; i += 256) {
    int j = bidD[i];
    ed[ld[j] + i - lofsD[j]] = edbuf[i];
  }
  for (int i = t; i < cnt; i += 256) {
    int j = bidS[i];
    ssk8[ls[j] + i - lofsS[j]] = ssbuf[i];
  }
}

// ------ P2: per-bucket CSR finalize + degrees/norms (padded bucket space) ----------
__global__ __launch_bounds__(256) void k_bucket_csr(const u32* __restrict__ ed,
                                                    const u8* __restrict__ ssk8,
                                                    const int* __restrict__ cur_d,
                                                    const int* __restrict__ cur_s,
                                                    int* __restrict__ row_ptr,
                                                    int* __restrict__ deg,
                                                    float* __restrict__ norm_in,
                                                    float* __restrict__ norm_out,
                                                    int* __restrict__ edge_src) {
  __shared__ int hist[256], scanbuf[256], cursor[256], hist2[256];
  const int b = blockIdx.x, t = threadIdx.x;
  const int base = b << 8;
  const int lo = b * CAP;
  const int hiD = lo + cur_d[b];   // cursors are relative counts
  const int hiS = lo + cur_s[b];
  hist[t] = 0; hist2[t] = 0;
  __syncthreads();
  for (int i = lo + t; i < hiS; i += 256) atomicAdd(&hist2[ssk8[i]], 1);
  for (int i = lo + t; i < hiD; i += 256) atomicAdd(&hist[ed[i] >> 24], 1);
  __syncthreads();
  int node = base + t;
  if (node < N_NODES)
    norm_out[node] = rsqrtf(fmaxf((float)hist2[t], 1.0f));
  int v = hist[t];
  scanbuf[t] = v;
  __syncthreads();
  for (int off = 1; off < 256; off <<= 1) {
    int a = (t >= off) ? scanbuf[t - off] : 0;
    __syncthreads(); scanbuf[t] += a; __syncthreads();
  }
  int excl = scanbuf[t] - v;
  if (node < N_NODES) {
    row_ptr[node] = lo + excl;
    deg[node] = v;
    norm_in[node] = rsqrtf(fmaxf((float)v, 1.0f));
  }
  cursor[t] = excl;
  __syncthreads();
  for (int i = lo + t; i < hiD; i += 256) {
    u32 e = ed[i];
    int p = atomicAdd(&cursor[e >> 24], 1);
    edge_src[lo + p] = (int)(e & 0x00FFFFFFu);
  }
}

// ---------------- P3: gemm1 (MFMA fp16): h1 = (x * norm_out) @ W1 -> fp16 ----------
__global__ __launch_bounds__(256) void k_gemm1(const float* __restrict__ x,
                                               const float* __restrict__ W1,
                                               const float* __restrict__ norm_out,
                                               __half* __restrict__ h1h) {
  __shared__ __align__(16) f16 Xs[64 * LDX];
  __shared__ __align__(16) f16 Ws[64 * LDX];
  const int t = threadIdx.x;
  const int row0 = blockIdx.x * 64;

  const float4* W4 = (const float4*)W1;     // 2048 float4 = [k][n4]
  for (int i = t; i < 2048; i += 256) {
    int k = i >> 4, n4 = (i & 15) * 4;
    float4 v = W4[i];
    Ws[(n4 + 0) * LDX + k] = (f16)v.x;
    Ws[(n4 + 1) * LDX + k] = (f16)v.y;
    Ws[(n4 + 2) * LDX + k] = (f16)v.z;
    Ws[(n4 + 3) * LDX + k] = (f16)v.w;
  }
  const float4* x4 = (const float4*)x;
  #pragma unroll
  for (int i = 0; i < 8; ++i) {
    int idx = t + 256 * i;                  // 0..2047
    int r = idx >> 5, c4 = idx & 31;
    int row = row0 + r;
    float4 v = make_float4(0.f, 0.f, 0.f, 0.f);
    if (row < N_NODES) {
      float s = norm_out[row];
      v = x4[(size_t)row * 32 + c4];
      v.x *= s; v.y *= s; v.z *= s; v.w *= s;
    }
    half4v h = { (f16)v.x, (f16)v.y, (f16)v.z, (f16)v.w };
    *(half4v*)&Xs[r * LDX + c4 * 4] = h;
  }
  __syncthreads();

  const int w = t >> 6, l = t & 63;
  const int m = l & 15, quad = l >> 4;
  floatx4 c0 = {0.f,0.f,0.f,0.f}, c1 = {0.f,0.f,0.f,0.f};
  floatx4 c2 = {0.f,0.f,0.f,0.f}, c3 = {0.f,0.f,0.f,0.f};
  const f16* xrow = &Xs[(w * 16 + m) * LDX + quad * 8];
  const f16* wrow = &Ws[m * LDX + quad * 8];
  #pragma unroll
  for (int kb = 0; kb < 4; ++kb) {
    half8 a  = *(const half8*)(xrow + kb * 32);
    half8 b0 = *(const half8*)(wrow + kb * 32);
    half8 b1 = *(const half8*)(wrow + 16 * LDX + kb * 32);
    half8 b2 = *(const half8*)(wrow + 32 * LDX + kb * 32);
    half8 b3 = *(const half8*)(wrow + 48 * LDX + kb * 32);
    c0 = __builtin_amdgcn_mfma_f32_16x16x32_f16(a, b0, c0, 0, 0, 0);
    c1 = __builtin_amdgcn_mfma_f32_16x16x32_f16(a, b1, c1, 0, 0, 0);
    c2 = __builtin_amdgcn_mfma_f32_16x16x32_f16(a, b2, c2, 0, 0, 0);
    c3 = __builtin_amdgcn_mfma_f32_16x16x32_f16(a, b3, c3, 0, 0, 0);
  }
  #pragma unroll
  for (int r = 0; r < 4; ++r) {
    int row = row0 + w * 16 + quad * 4 + r;
    if (row < N_NODES + 1) {                // includes zeros dummy row N_NODES
      __half* dst = h1h + (size_t)row * 64 + m;
      dst[0]  = __float2half(c0[r]);
      dst[16] = __float2half(c1[r]);
      dst[32] = __float2half(c2[r]);
      dst[48] = __float2half(c3[r]);
    }
  }
}

// ---------------- P4: fused gather(h1) -> relu -> @W2 -> h2, all-register MFMA ----
// R8 MFMA body + LDS edge-index staging + depth-2 load slots: the wave's edge
// list is staged into LDS once (coalesced), so the gather loop's h1 loads have
// no global->global dependency and two chunk-slots (8 dwordx4) stay in flight.
__global__ __launch_bounds__(256) void k_gather_l1(const int* __restrict__ row_ptr,
                                                   const int* __restrict__ deg,
                                                   const int* __restrict__ edge_src,
                                                   const __half* __restrict__ h1h,
                                                   const float* __restrict__ norm_in,
                                                   const float* __restrict__ norm_out,
                                                   const float* __restrict__ b1,
                                                   const float* __restrict__ W2,
                                                   __half* __restrict__ h2h) {
  __shared__ __align__(16) f16 Ws2[16 * 72];      // W2^T [n][k], stride 72
  __shared__ __align__(16) f16 Rs[4][16 * 72];    // per-wave relu vecs [node][feat]
  __shared__ int Eidx[4][EW];                     // per-wave staged edge list
  const int t = threadIdx.x;
  for (int i = t; i < 1024; i += 256) {           // W2 [64][16] row-major
    int k = i >> 4, n = i & 15;
    Ws2[n * 72 + k] = (f16)W2[i];
  }
  if (blockIdx.x == 0 && t < 16) h2h[(size_t)N_NODES * 16 + t] = __float2half(0.f);
  __syncthreads();

  const int w = t >> 6, l = t & 63;
  const int base = blockIdx.x * 64 + w * 16;
  if (base >= N_NODES) return;

  const int m = l & 15, q4 = l >> 4;              // fragment coords
  const int node_l = min(base + m, N_NODES - 1);
  const int my_lo = row_ptr[node_l];
  const u32 my_deg = (u32)deg[node_l];
  const int lo_blk = __shfl(my_lo, 0, 64);
  const int hi_blk = __shfl(my_lo + (int)my_deg, 15, 64);
  const int nE = min(hi_blk - lo_blk, EW);        // EW = mean+20sigma, never binds

  // stage the wave's edge list (coalesced, sequential)
  for (int i = l; i < nE; i += 64) Eidx[w][i] = edge_src[lo_blk + i];
  asm volatile("s_waitcnt lgkmcnt(0)" ::: "memory");
  __builtin_amdgcn_sched_barrier(0);

  // gather permutations: lane's A-row m -> chunk-local edge sigma(m)
  const int s1e = 8 * (m >> 2) + (m & 3);
  const int s2e = s1e + 4;

  union U4 { u32 u[4]; half8 h; uint4 v; };

  // loop-invariant identity B-frags for stage1: B_ih[k][n] = (k == n + 16*ih)
  U4 ib0, ib1;
  #pragma unroll
  for (int wj = 0; wj < 4; ++wj) {
    int k0 = q4 * 8 + 2 * wj, k1 = k0 + 1;
    ib0.u[wj] = (k0 == m      ? 0x3C00u : 0u) | (k1 == m      ? 0x3C000000u : 0u);
    ib1.u[wj] = (k0 == m + 16 ? 0x3C00u : 0u) | (k1 == m + 16 ? 0x3C000000u : 0u);
  }

  const uint4* __restrict__ h1u4 = (const uint4*)h1h;
  floatx4 acc0 = {0.f,0.f,0.f,0.f}, acc1 = {0.f,0.f,0.f,0.f};
  floatx4 acc2 = {0.f,0.f,0.f,0.f}, acc3 = {0.f,0.f,0.f,0.f};
  const floatx4 zf = {0.f,0.f,0.f,0.f};

  uint4 pa0, pa1, pb0, pb1;   // slot A
  uint4 qa0, qa1, qb0, qb1;   // slot B
  #define LOADC(CB, R0, R1, R2, R3) do {                                      \
    int o1 = (CB) + s1e, o2 = (CB) + s2e;                                     \
    int sv1 = (o1 < nE) ? Eidx[w][o1] : (int)N_NODES;                         \
    int sv2 = (o2 < nE) ? Eidx[w][o2] : (int)N_NODES;                         \
    size_t r1 = (size_t)(u32)sv1 * 8u, r2 = (size_t)(u32)sv2 * 8u;            \
    R0 = h1u4[r1 + (u32)q4];       R1 = h1u4[r1 + 4u + (u32)q4];              \
    R2 = h1u4[r2 + (u32)q4];       R3 = h1u4[r2 + 4u + (u32)q4];              \
  } while (0)

  // 12 MFMAs for one 32-edge chunk held in (CA0,CA1,CB0,CB1), flags from E0
  #define CHUNK_MFMA(E0, CA0, CA1, CB0, CB1) do {                             \
    u32 e0 = (E0) + (u32)(q4 * 8);                                            \
    U4 s;                                                                     \
    s.u[0] = ((e0+0u)<my_deg?0x3C00u:0u) | ((e0+1u)<my_deg?0x3C000000u:0u);   \
    s.u[1] = ((e0+2u)<my_deg?0x3C00u:0u) | ((e0+3u)<my_deg?0x3C000000u:0u);   \
    s.u[2] = ((e0+4u)<my_deg?0x3C00u:0u) | ((e0+5u)<my_deg?0x3C000000u:0u);   \
    s.u[3] = ((e0+6u)<my_deg?0x3C00u:0u) | ((e0+7u)<my_deg?0x3C000000u:0u);   \
    {                                                                         \
      floatx4 o10 = __builtin_amdgcn_mfma_f32_16x16x32_f16(CA0.h, ib0.h, zf, 0, 0, 0); \
      floatx4 o11 = __builtin_amdgcn_mfma_f32_16x16x32_f16(CA0.h, ib1.h, zf, 0, 0, 0); \
      floatx4 o20 = __builtin_amdgcn_mfma_f32_16x16x32_f16(CB0.h, ib0.h, zf, 0, 0, 0); \
      floatx4 o21 = __builtin_amdgcn_mfma_f32_16x16x32_f16(CB0.h, ib1.h, zf, 0, 0, 0); \
      half8 bf0 = { (f16)o10[0], (f16)o10[1], (f16)o10[2], (f16)o10[3],       \
                    (f16)o20[0], (f16)o20[1], (f16)o20[2], (f16)o20[3] };     \
      half8 bf1 = { (f16)o11[0], (f16)o11[1], (f16)o11[2], (f16)o11[3],       \
                    (f16)o21[0], (f16)o21[1], (f16)o21[2], (f16)o21[3] };     \
      acc0 = __builtin_amdgcn_mfma_f32_16x16x32_f16(s.h, bf0, acc0, 0, 0, 0); \
      acc1 = __builtin_amdgcn_mfma_f32_16x16x32_f16(s.h, bf1, acc1, 0, 0, 0); \
    }                                                                         \
    {                                                                         \
      floatx4 o10 = __builtin_amdgcn_mfma_f32_16x16x32_f16(CA1.h, ib0.h, zf, 0, 0, 0); \
      floatx4 o11 = __builtin_amdgcn_mfma_f32_16x16x32_f16(CA1.h, ib1.h, zf, 0, 0, 0); \
      floatx4 o20 = __builtin_amdgcn_mfma_f32_16x16x32_f16(CB1.h, ib0.h, zf, 0, 0, 0); \
      floatx4 o21 = __builtin_amdgcn_mfma_f32_16x16x32_f16(CB1.h, ib1.h, zf, 0, 0, 0); \
      half8 bf0 = { (f16)o10[0], (f16)o10[1], (f16)o10[2], (f16)o10[3],       \
                    (f16)o20[0], (f16)o20[1], (f16)o20[2], (f16)o20[3] };     \
      half8 bf1 = { (f16)o11[0], (f16)o11[1], (f16)o11[2], (f16)o11[3],       \
                    (f16)o21[0], (f16)o21[1], (f16)o21[2], (f16)o21[3] };     \
      acc2 = __builtin_amdgcn_mfma_f32_16x16x32_f16(s.h, bf0, acc2, 0, 0, 0); \
      acc3 = __builtin_amdgcn_mfma_f32_16x16x32_f16(s.h, bf1, acc3, 0, 0, 0); \
    }                                                                         \
  } while (0)

  // prologue: fill both slots (clamped loads past nE hit the zeros row)
  LOADC(0,  pa0, pa1, pb0, pb1);
  LOADC(32, qa0, qa1, qb0, qb1);

  const u32 dlo = (u32)(lo_blk - my_lo);          // wraps; flags mask correctly
  #pragma unroll 1
  for (int cb = 0; cb < nE; cb += 64) {
    U4 ca0, ca1, cb0v, cb1v;
    ca0.v = pa0; ca1.v = pa1; cb0v.v = pb0; cb1v.v = pb1;
    LOADC(cb + 64, pa0, pa1, pb0, pb1);
    CHUNK_MFMA(dlo + (u32)cb, ca0, ca1, cb0v, cb1v);

    U4 da0, da1, db0, db1;
    da0.v = qa0; da1.v = qa1; db0.v = qb0; db1.v = qb1;
    LOADC(cb + 96, qa0, qa1, qb0, qb1);
    CHUNK_MFMA(dlo + (u32)(cb + 32), da0, da1, db0, db1);
  }
  #undef LOADC
  #undef CHUNK_MFMA

  // epilogue: D rows = nodes (q4*4+r), cols = feats 16g+m. relu(*ni + b1) -> Rs
  const float bg0 = b1[m], bg1 = b1[16 + m], bg2 = b1[32 + m], bg3 = b1[48 + m];
  f16* Rw = &Rs[w][0];
  #pragma unroll
  for (int r = 0; r < 4; ++r) {
    int row = base + q4 * 4 + r;
    float ni = (row < N_NODES) ? norm_in[row] : 0.f;
    f16* dst = &Rw[(q4 * 4 + r) * 72 + m];
    dst[0]  = (f16)fmaxf(acc0[r] * ni + bg0, 0.f);
    dst[16] = (f16)fmaxf(acc1[r] * ni + bg1, 0.f);
    dst[32] = (f16)fmaxf(acc2[r] * ni + bg2, 0.f);
    dst[48] = (f16)fmaxf(acc3[r] * ni + bg3, 0.f);
  }
  // drain the per-wave ds_writes before the cross-lane ds_reads of the tail
  asm volatile("s_waitcnt lgkmcnt(0)" ::: "memory");
  __builtin_amdgcn_sched_barrier(0);

  // W2 MFMA tail (same fragment indexing as k_gemm1), per-wave on its own Rs
  const f16* ra = &Rw[m * 72 + q4 * 8];
  const f16* rb = &Ws2[m * 72 + q4 * 8];
  half8 a0 = *(const half8*)ra;
  half8 a1 = *(const half8*)(ra + 32);
  half8 wb0 = *(const half8*)rb;
  half8 wb1 = *(const half8*)(rb + 32);
  floatx4 cc = {0.f,0.f,0.f,0.f};
  cc = __builtin_amdgcn_mfma_f32_16x16x32_f16(a0, wb0, cc, 0, 0, 0);
  cc = __builtin_amdgcn_mfma_f32_16x16x32_f16(a1, wb1, cc, 0, 0, 0);
  #pragma unroll
  for (int r = 0; r < 4; ++r) {
    int row = base + q4 * 4 + r;
    if (row < N_NODES)
      h2h[(size_t)row * 16 + m] = __float2half(cc[r] * norm_out[row]);
  }
}

// ---------------- P5: gather layer2: agg2 = norm_in * sum_edges h2[src] (16 feats) ------
__global__ __launch_bounds__(256) void k_gather_l2(const int* __restrict__ row_ptr,
                                                   const int* __restrict__ deg,
                                                   const int* __restrict__ edge_src,
                                                   const __half* __restrict__ h2h,
                                                   const float* __restrict__ norm_in,
                                                   float* __restrict__ agg2) {
  const int t = threadIdx.x;
  const int w = t >> 6;
  const int l = t & 63;
  const int n = blockIdx.x * 4 + w;
  const int f2 = l & 7;
  const int p = l >> 3;            // 8 edge slices

  const u32* __restrict__ h2u = (const u32*)h2h;
  const int lo = row_ptr[n], hi = lo + deg[n];

  float ax = 0.f, ay = 0.f, bx = 0.f, by = 0.f;
  for (int base = lo; base < hi; base += 16) {
    int i1 = base + p, i2 = base + p + 8;
    int s0 = (i1 < hi) ? edge_src[i1] : (int)N_NODES;
    int s1 = (i2 < hi) ? edge_src[i2] : (int)N_NODES;
    u32 v0 = h2u[(u32)s0 * 8u + (u32)f2];
    u32 v1 = h2u[(u32)s1 * 8u + (u32)f2];
    float2 g0 = __half22float2(*(__half2*)&v0);
    float2 g1 = __half22float2(*(__half2*)&v1);
    ax += g0.x; ay += g0.y;
    bx += g1.x; by += g1.y;
  }
  float sx = ax + bx, sy = ay + by;
  sx += __shfl_xor(sx, 8, 64);  sy += __shfl_xor(sy, 8, 64);
  sx += __shfl_xor(sx, 16, 64); sy += __shfl_xor(sy, 16, 64);
  sx += __shfl_xor(sx, 32, 64); sy += __shfl_xor(sy, 32, 64);
  if (l < 8) {
    float ni = norm_in[n];
    ((float2*)agg2)[(size_t)n * 8 + f2] = make_float2(sx * ni, sy * ni);
  }
}

// ---------------- P6: per-graph mean pool (gid sorted, no atomics) ----------------
__global__ __launch_bounds__(256) void k_pool(const float* __restrict__ agg2,
                                              const float* __restrict__ b2,
                                              const int* __restrict__ gid,
                                              float* __restrict__ out) {
  const int g = blockIdx.x;
  __shared__ int s_lo, s_hi;
  if (threadIdx.x == 0) {
    int a = 0, b = N_NODES;
    while (a < b) { int m = (a + b) >> 1; if (gid[m] < g) a = m + 1; else b = m; }
    s_lo = a;
    b = N_NODES;
    while (a < b) { int m = (a + b) >> 1; if (gid[m] < g + 1) a = m + 1; else b = m; }
    s_hi = a;
  }
  __syncthreads();
  const int lo = s_lo, hi = s_hi, cnt = hi - lo;
  const int j = threadIdx.x & 15;
  const int r = threadIdx.x >> 4;
  float acc = 0.f;
  for (int n = lo + r; n < hi; n += 16)
    acc += agg2[(size_t)n * 16 + j];

  __shared__ float red[256];
  red[threadIdx.x] = acc;
  __syncthreads();
  #pragma unroll
  for (int s = 8; s > 0; s >>= 1) {
    if (r < s) red[threadIdx.x] += red[threadIdx.x + s * 16];
    __syncthreads();
  }
  if (r == 0)
    out[g * 16 + j] = (cnt > 0) ? (red[j] / (float)cnt + b2[j]) : 0.0f;
}

extern "C" void kernel_launch(void* const* d_in, const int* in_sizes, int n_in,
                              void* d_out, int out_size, void* d_ws, size_t ws_size,
                              hipStream_t stream) {
  const float* x   = (const float*)d_in[0];
  const float* W1  = (const float*)d_in[1];
  const float* b1  = (const float*)d_in[2];
  const float* W2  = (const float*)d_in[3];
  const float* b2  = (const float*)d_in[4];
  const int*   src = (const int*)d_in[5];
  const int*   dst = (const int*)d_in[6];
  const int*   gid = (const int*)d_in[7];
  float* out = (float*)d_out;

  int* wsi = (int*)d_ws;
  float* wsf = (float*)d_ws;

  // word-offset layout (~24.8 MB):
  float* norm_out = wsf + 0;                 // [N]
  float* norm_in  = wsf + 100000;            // [N]
  int*   row_ptr  = wsi + 200000;            // [N]
  int*   deg      = wsi + 300000;            // [N]
  int*   cur_d    = wsi + 400000;            // [SB+pad] (relative counts)
  int*   cur_s    = wsi + 400400;            // [SB+pad]
  int*   edge_src = wsi + 400800;            // [SB*CAP = 1801728] padded bucket space
  const size_t S  = 2202528;                 // scratch base (words)
  // sort scratch (dead after k_bucket_csr):
  u8*    ssk8     = (u8*)(wsi + S);          // [SB*CAP bytes = 450432 words]
  u32*   ed       = (u32*)(wsi + S + 450432);// [SB*CAP = 1801728]
  // reuse after CSR build: h1h over {ssk8,ed}; agg2 over dead h1h; h2h after h1h
  __half* h1h     = (__half*)(wsi + S);            // [(N+1)*64 halves = 3200032 words]
  __half* h2h     = (__half*)(wsi + S + 3200032);  // [(N+1)*16 halves = 800008 words]
  float*  agg2    = (float*)(wsi + S);             // [16N words] (h1h dead by then)

  const int4* src4 = (const int4*)src;
  const int4* dst4 = (const int4*)dst;

  hipMemsetAsync(cur_d, 0, 800 * sizeof(int), stream);   // zero cur_d + cur_s
  k_fuse      <<<NBLK, 256, 0, stream>>>(src4, dst4, cur_d, cur_s, ed, ssk8);
  k_bucket_csr<<<SB, 256, 0, stream>>>(ed, ssk8, cur_d, cur_s, row_ptr, deg,
                                       norm_in, norm_out, edge_src);
  k_gemm1     <<<(N_NODES + 64) / 64, 256, 0, stream>>>(x, W1, norm_out, h1h);
  k_gather_l1 <<<(N_NODES + 63) / 64, 256, 0, stream>>>(row_ptr, deg, edge_src, h1h,
                                                        norm_in, norm_out, b1, W2, h2h);
  k_gather_l2 <<<N_NODES / 4, 256, 0, stream>>>(row_ptr, deg, edge_src, h2h,
                                                norm_in, agg2);
  k_pool      <<<N_GRAPHS, 256, 0, stream>>>(agg2, b2, gid, out);
}